// Round 8
// baseline (98.436 us; speedup 1.0000x reference)
//
#include <hip/hip_runtime.h>
#include <math.h>

#define BB 2
#define SS 2048
#define EE 1024
#define HH 16
#define DD 64
constexpr int NROWS = BB * SS * HH;   // 65536 rows of D=64
// q pre-scale: (1/sqrt(E)) * log2(e) so attention can use exp2 directly
constexpr float SCALE_Q = 1.4426950408889634f / 32.0f;

typedef __attribute__((ext_vector_type(8))) short bf16x8;
typedef __attribute__((ext_vector_type(4))) float f32x4;
typedef __attribute__((ext_vector_type(16))) float f32x16;
typedef __attribute__((ext_vector_type(4))) unsigned u32x4;

__device__ inline ushort f2bf(float f) {
  unsigned u = __builtin_bit_cast(unsigned, f);
  u += 0x7fffu + ((u >> 16) & 1u);   // RNE
  return (ushort)(u >> 16);
}

// packed f32x2 -> bf16x2 (RNE), one VALU inst
__device__ inline unsigned cvt_pk(float lo, float hi) {
  unsigned r;
  asm("v_cvt_pk_bf16_f32 %0, %1, %2" : "=v"(r) : "v"(lo), "v"(hi));
  return r;
}

// ---------------------------------------------------------------------------
// Kernel 0: Wq/Wk/Wv fp32 -> bf16 (12288 elems), once.
// ---------------------------------------------------------------------------
__global__ __launch_bounds__(256) void wqkv_cvt(
    const float* __restrict__ Wq, const float* __restrict__ Wk,
    const float* __restrict__ Wv, ushort* __restrict__ o) {
  int i = blockIdx.x * 256 + threadIdx.x;  // grid 48 * 256 = 12288
  int t = i >> 12, j = i & 4095;
  const float* W = (t == 0) ? Wq : ((t == 1) ? Wk : Wv);
  o[i] = f2bf(W[j]);
}

// ---------------------------------------------------------------------------
// Kernel 1: QKV projection, h-major blocks (fixed b,h; 128 s-rows).
// q,k written [B,S,H,D]; V written TRANSPOSED [B,H,D,S] directly.
// ---------------------------------------------------------------------------
__global__ __launch_bounds__(256) void qkv_mfma(
    const float* __restrict__ x, const ushort* __restrict__ wqkv,
    ushort* __restrict__ qo, ushort* __restrict__ ko, ushort* __restrict__ vto) {
  __shared__ __align__(16) ushort Xs[128 * 72];
  __shared__ __align__(16) ushort Ws[3][64 * 72];
  const int tid = threadIdx.x, w = tid >> 6, l = tid & 63;
  const int g = l >> 4, c = l & 15;
  const int s0 = blockIdx.x * 128, h = blockIdx.y, b = blockIdx.z;

  for (int i = tid; i < 1536; i += 256) {
    int t = i >> 9, j = i & 511;
    int r = j >> 3, e0 = (j & 7) * 8;
    *(bf16x8*)&Ws[t][r * 72 + e0] = *(const bf16x8*)&wqkv[t * 4096 + r * 64 + e0];
  }
  for (int i = tid; i < 2048; i += 256) {
    int r = i >> 4, c4 = (i & 15) * 4;
    float4 xv = *(const float4*)&x[(((size_t)b * SS + s0 + r) * HH + h) * DD + c4];
    uint2 pk;
    pk.x = cvt_pk(xv.x, xv.y);
    pk.y = cvt_pk(xv.z, xv.w);
    *(uint2*)&Xs[r * 72 + c4] = pk;
  }
  __syncthreads();

  bf16x8 a_[2][2];
#pragma unroll
  for (int rf = 0; rf < 2; ++rf) {
    a_[rf][0] = *(bf16x8*)&Xs[(w * 32 + rf * 16 + c) * 72 + g * 8];
    a_[rf][1] = *(bf16x8*)&Xs[(w * 32 + rf * 16 + c) * 72 + 32 + g * 8];
  }

  // q and k: row-major [B,S,H,D]
#pragma unroll
  for (int t = 0; t < 2; ++t) {
    ushort* out = (t == 0) ? qo : ko;
    const float sc = (t == 0) ? SCALE_Q : 1.0f;
#pragma unroll
    for (int ct = 0; ct < 4; ++ct) {
      bf16x8 b0 = *(bf16x8*)&Ws[t][(ct * 16 + c) * 72 + g * 8];
      bf16x8 b1 = *(bf16x8*)&Ws[t][(ct * 16 + c) * 72 + 32 + g * 8];
#pragma unroll
      for (int rf = 0; rf < 2; ++rf) {
        f32x4 acc = (f32x4){0.f, 0.f, 0.f, 0.f};
        acc = __builtin_amdgcn_mfma_f32_16x16x32_bf16(a_[rf][0], b0, acc, 0, 0, 0);
        acc = __builtin_amdgcn_mfma_f32_16x16x32_bf16(a_[rf][1], b1, acc, 0, 0, 0);
#pragma unroll
        for (int r = 0; r < 4; ++r) {
          int srow = w * 32 + rf * 16 + g * 4 + r;
          out[(((size_t)b * SS + s0 + srow) * HH + h) * DD + ct * 16 + c] =
              f2bf(acc[r] * sc);
        }
      }
    }
  }
  // v: transposed [B,H,D,S], packed 8B stores
#pragma unroll
  for (int ct = 0; ct < 4; ++ct) {
    bf16x8 b0 = *(bf16x8*)&Ws[2][(ct * 16 + c) * 72 + g * 8];
    bf16x8 b1 = *(bf16x8*)&Ws[2][(ct * 16 + c) * 72 + 32 + g * 8];
#pragma unroll
    for (int rf = 0; rf < 2; ++rf) {
      f32x4 acc = (f32x4){0.f, 0.f, 0.f, 0.f};
      acc = __builtin_amdgcn_mfma_f32_16x16x32_bf16(a_[rf][0], b0, acc, 0, 0, 0);
      acc = __builtin_amdgcn_mfma_f32_16x16x32_bf16(a_[rf][1], b1, acc, 0, 0, 0);
      uint2 pk;
      pk.x = cvt_pk(acc[0], acc[1]);
      pk.y = cvt_pk(acc[2], acc[3]);
      int d = ct * 16 + c;
      int srow = w * 32 + rf * 16 + g * 4;
      *(uint2*)&vto[(((size_t)b * HH + h) * DD + d) * SS + s0 + srow] = pk;
    }
  }
}

// ---------------------------------------------------------------------------
// Kernel 3: W_out fp32 -> bf16
// ---------------------------------------------------------------------------
__global__ __launch_bounds__(256) void wcvt(const float* __restrict__ w,
                                            ushort* __restrict__ o) {
  int i = (blockIdx.x * 256 + threadIdx.x) * 8;
  bf16x8 t;
#pragma unroll
  for (int j = 0; j < 8; ++j) t[j] = (short)f2bf(w[i + j]);
  *(bf16x8*)&o[i] = t;
}

// ---------------------------------------------------------------------------
// Kernel 4: MFMA flash attention, 32x32x16, swapped S^T = K·Q^T, KEY-SPLIT 2.
// Each block: one (b,h,q-tile,split) over 1024 keys -> 1024 blocks = 4/CU
// (occupancy 2x vs r7). Sum-normalized softmax => partials exactly additive:
// write fp32 unnormalized O-partial + row-sum; combine kernel finishes.
// ---------------------------------------------------------------------------
__global__ __launch_bounds__(256) void attn_mfma(
    const ushort* __restrict__ q, const ushort* __restrict__ k,
    const ushort* __restrict__ vt, float* __restrict__ pO,
    float* __restrict__ lsum) {
  __shared__ __align__(16) ushort Ks[2][64 * 72];
  __shared__ __align__(16) ushort Vts[2][64 * 72];
  const int tid = threadIdx.x, w = tid >> 6, l = tid & 63;
  const int lq = l & 31, h2 = l >> 5;  // q-col, lane half
  // XCD swizzle: blockIdx%8 = XCD -> contiguous chunk of 128 works
  const int work = ((blockIdx.x & 7) << 7) | (blockIdx.x >> 3);
  const int qt = work & 15;            // q-tile
  const int split = (work >> 4) & 1;   // key half
  const int hb = work >> 5;
  const int h = hb & 15, b = hb >> 4;
  const int q0 = qt * 128;
  const int k0base = split * 1024;

  const size_t bh_qk = (size_t)b * SS * EE + h * DD;        // + s*EE + d
  const size_t bh_vt = (size_t)b * SS * EE + h * (DD * SS); // + d*SS + s
  const size_t kq_base = bh_qk + (size_t)k0base * EE;
  const size_t vt_base = bh_vt + k0base;

  const int sr0 = tid >> 3;            // 0..31
  const int se0 = (tid & 7) * 8;
  // sigma: swap bits 2 and 3 of the key index (bits 0,1,4 kept)
  const int krow0 = (sr0 & 19) | ((sr0 & 4) << 1) | ((sr0 & 8) >> 1);

  // prologue: stage tile 0 of this split
  {
    bf16x8 kr0 = *(const bf16x8*)&k[kq_base + (size_t)sr0 * EE + se0];
    bf16x8 kr1 = *(const bf16x8*)&k[kq_base + (size_t)(sr0 + 32) * EE + se0];
    bf16x8 vr0 = *(const bf16x8*)&vt[vt_base + (size_t)sr0 * SS + se0];
    bf16x8 vr1 = *(const bf16x8*)&vt[vt_base + (size_t)(sr0 + 32) * SS + se0];
    *(bf16x8*)&Ks[0][krow0 * 72 + se0] = kr0;
    *(bf16x8*)&Ks[0][(krow0 + 32) * 72 + se0] = kr1;
    *(bf16x8*)&Vts[0][sr0 * 72 + se0] = vr0;
    *(bf16x8*)&Vts[0][(sr0 + 32) * 72 + se0] = vr1;
  }

  // Q B-frags direct from global: lane's q-row = q0 + w*32 + lq
  bf16x8 aq[4];
#pragma unroll
  for (int db = 0; db < 4; ++db)
    aq[db] = *(const bf16x8*)&q[bh_qk +
        (size_t)(q0 + w * 32 + lq) * EE + db * 16 + h2 * 8];

  f32x16 accO[2];
  float lacc[2] = {0.f, 0.f};
#pragma unroll
  for (int ct = 0; ct < 2; ++ct)
#pragma unroll
    for (int r = 0; r < 16; ++r) accO[ct][r] = 0.f;

  __syncthreads();

  for (int t = 0; t < 16; ++t) {
    const int cur = t & 1;
    bf16x8 kr0, kr1, vr0, vr1;
    if (t < 15) {  // issue next tile's loads; latency hides under MFMAs
      const size_t kb2 = kq_base + (size_t)((t + 1) * 64) * EE;
      kr0 = *(const bf16x8*)&k[kb2 + (size_t)sr0 * EE + se0];
      kr1 = *(const bf16x8*)&k[kb2 + (size_t)(sr0 + 32) * EE + se0];
      const size_t vb2 = vt_base + (t + 1) * 64;
      vr0 = *(const bf16x8*)&vt[vb2 + (size_t)sr0 * SS + se0];
      vr1 = *(const bf16x8*)&vt[vb2 + (size_t)(sr0 + 32) * SS + se0];
    }

    // S^T = K Q^T: 2 key-blocks x 4 depth-blocks
    f32x16 s[2];
    __builtin_amdgcn_s_setprio(1);
#pragma unroll
    for (int kb = 0; kb < 2; ++kb) {
      f32x16 acc;
#pragma unroll
      for (int r = 0; r < 16; ++r) acc[r] = 0.f;
#pragma unroll
      for (int db = 0; db < 4; ++db) {
        bf16x8 ka = *(bf16x8*)&Ks[cur][(kb * 32 + lq) * 72 + db * 16 + h2 * 8];
        acc = __builtin_amdgcn_mfma_f32_32x32x16_bf16(ka, aq[db], acc, 0, 0, 0);
      }
      s[kb] = acc;
    }
    __builtin_amdgcn_s_setprio(0);

    // p = exp2(s); regs t16*8 + j are exactly PV B-frag key order
    u32x4 pwv[2][2];  // [kb][t16]
#pragma unroll
    for (int kb = 0; kb < 2; ++kb)
#pragma unroll
      for (int t16 = 0; t16 < 2; ++t16)
#pragma unroll
        for (int j2 = 0; j2 < 4; ++j2) {
          float pa = __builtin_amdgcn_exp2f(s[kb][t16 * 8 + j2 * 2]);
          float pb = __builtin_amdgcn_exp2f(s[kb][t16 * 8 + j2 * 2 + 1]);
          lacc[kb] += pa + pb;
          pwv[kb][t16][j2] = cvt_pk(pa, pb);
        }

    // O^T += V^T P^T
    __builtin_amdgcn_s_setprio(1);
#pragma unroll
    for (int ct = 0; ct < 2; ++ct) {
#pragma unroll
      for (int kb = 0; kb < 2; ++kb)
#pragma unroll
        for (int t16 = 0; t16 < 2; ++t16) {
          bf16x8 va = *(bf16x8*)&Vts[cur][(ct * 32 + lq) * 72 +
                                          kb * 32 + t16 * 16 + h2 * 8];
          accO[ct] = __builtin_amdgcn_mfma_f32_32x32x16_bf16(
              va, __builtin_bit_cast(bf16x8, pwv[kb][t16]), accO[ct], 0, 0, 0);
        }
    }
    __builtin_amdgcn_s_setprio(0);

    // write next tile into the other buffer (vmcnt hidden under MFMAs)
    if (t < 15) {
      const int nxt = cur ^ 1;
      *(bf16x8*)&Ks[nxt][krow0 * 72 + se0] = kr0;
      *(bf16x8*)&Ks[nxt][(krow0 + 32) * 72 + se0] = kr1;
      *(bf16x8*)&Vts[nxt][sr0 * 72 + se0] = vr0;
      *(bf16x8*)&Vts[nxt][(sr0 + 32) * 72 + se0] = vr1;
    }
    __syncthreads();
  }

  // epilogue: h2 halves hold complementary key subsets; reduce row sum,
  // write fp32 partial O (unnormalized) + row sum for this split.
  {
    float tsum = lacc[0] + lacc[1];
    tsum += __shfl_xor(tsum, 32, 64);
    const int qrow = q0 + w * 32 + lq;
    if (h2 == 0)
      lsum[((size_t)split * BB * HH + (size_t)b * HH + h) * SS + qrow] = tsum;
    float* dst = pO + (size_t)split * NROWS * 64 +
                 ((size_t)b * SS + qrow) * EE + h * DD;
#pragma unroll
    for (int ct = 0; ct < 2; ++ct)
#pragma unroll
      for (int rq = 0; rq < 4; ++rq) {
        float4 v4 = {accO[ct][rq * 4 + 0], accO[ct][rq * 4 + 1],
                     accO[ct][rq * 4 + 2], accO[ct][rq * 4 + 3]};
        *(float4*)&dst[ct * 32 + rq * 8 + h2 * 4] = v4;
      }
  }
}

// ---------------------------------------------------------------------------
// Kernel 4b: combine the two key-split partials: o = (a0+a1)/(l0+l1), bf16.
// ---------------------------------------------------------------------------
__global__ __launch_bounds__(256) void attn_combine(
    const float* __restrict__ pO, const float* __restrict__ lsum,
    ushort* __restrict__ o) {
  const int gid = blockIdx.x * 256 + threadIdx.x;  // 0..524287
#pragma unroll
  for (int j = 0; j < 2; ++j) {
    const int idx = gid * 2 + j;           // quad index, 0..1048575
    const int e4 = idx * 4;                // element index
    const int row = e4 >> 10;              // 0..4095 (b*S+s)
    const int e = e4 & 1023;
    const int h = e >> 6;
    const int b = row >> 11, s = row & 2047;
    float4 a0 = *(const float4*)&pO[e4];
    float4 a1 = *(const float4*)&pO[(size_t)NROWS * 64 + e4];
    const size_t li = ((size_t)b * HH + h) * SS + s;
    float inv = 1.f / (lsum[li] + lsum[(size_t)BB * HH * SS + li]);
    uint2 pk;
    pk.x = cvt_pk((a0.x + a1.x) * inv, (a0.y + a1.y) * inv);
    pk.y = cvt_pk((a0.z + a1.z) * inv, (a0.w + a1.w) * inv);
    *(uint2*)&o[e4] = pk;
  }
}

// ---------------------------------------------------------------------------
// Kernel 5: output projection, bf16 MFMA GEMM, 128x64 tile, reg-staged
// double-buffer, 1 barrier per K-step.
// ---------------------------------------------------------------------------
__global__ __launch_bounds__(256) void out_proj_mfma(
    const ushort* __restrict__ a, const ushort* __restrict__ wo,
    const float* __restrict__ bias, float* __restrict__ y) {
  __shared__ __align__(16) ushort As[2][128 * 72];
  __shared__ __align__(16) ushort Ws[2][64 * 72];
  const int tid = threadIdx.x, w = tid >> 6, l = tid & 63;
  const int g = l >> 4, c = l & 15;
  const int m0 = blockIdx.x * 128, n0 = blockIdx.y * 64;
  const int sr = tid >> 3, se = (tid & 7) * 8;

  f32x4 acc[2][4];
#pragma unroll
  for (int mf = 0; mf < 2; ++mf)
#pragma unroll
    for (int ct = 0; ct < 4; ++ct) acc[mf][ct] = (f32x4){0.f, 0.f, 0.f, 0.f};

  {
#pragma unroll
    for (int j = 0; j < 4; ++j) {
      int r = sr + j * 32;
      *(bf16x8*)&As[0][r * 72 + se] = *(const bf16x8*)&a[(size_t)(m0 + r) * EE + se];
    }
#pragma unroll
    for (int j = 0; j < 2; ++j) {
      int r = sr + j * 32;
      *(bf16x8*)&Ws[0][r * 72 + se] = *(const bf16x8*)&wo[(size_t)(n0 + r) * EE + se];
    }
  }
  __syncthreads();

  for (int t = 0; t < 16; ++t) {
    const int cur = t & 1;
    bf16x8 Arg[4], Brg[2];
    if (t < 15) {
      const int k0 = (t + 1) * 64;
#pragma unroll
      for (int j = 0; j < 4; ++j) {
        int r = sr + j * 32;
        Arg[j] = *(const bf16x8*)&a[(size_t)(m0 + r) * EE + k0 + se];
      }
#pragma unroll
      for (int j = 0; j < 2; ++j) {
        int r = sr + j * 32;
        Brg[j] = *(const bf16x8*)&wo[(size_t)(n0 + r) * EE + k0 + se];
      }
    }

    bf16x8 af[2][2];
#pragma unroll
    for (int mf = 0; mf < 2; ++mf) {
      af[mf][0] = *(bf16x8*)&As[cur][(w * 32 + mf * 16 + c) * 72 + g * 8];
      af[mf][1] = *(bf16x8*)&As[cur][(w * 32 + mf * 16 + c) * 72 + 32 + g * 8];
    }
    __builtin_amdgcn_s_setprio(1);
#pragma unroll
    for (int ct = 0; ct < 4; ++ct) {
      bf16x8 b0 = *(bf16x8*)&Ws[cur][(ct * 16 + c) * 72 + g * 8];
      bf16x8 b1 = *(bf16x8*)&Ws[cur][(ct * 16 + c) * 72 + 32 + g * 8];
#pragma unroll
      for (int mf = 0; mf < 2; ++mf) {
        acc[mf][ct] = __builtin_amdgcn_mfma_f32_16x16x32_bf16(af[mf][0], b0, acc[mf][ct], 0, 0, 0);
        acc[mf][ct] = __builtin_amdgcn_mfma_f32_16x16x32_bf16(af[mf][1], b1, acc[mf][ct], 0, 0, 0);
      }
    }
    __builtin_amdgcn_s_setprio(0);

    if (t < 15) {
      const int nxt = cur ^ 1;
#pragma unroll
      for (int j = 0; j < 4; ++j) {
        int r = sr + j * 32;
        *(bf16x8*)&As[nxt][r * 72 + se] = Arg[j];
      }
#pragma unroll
      for (int j = 0; j < 2; ++j) {
        int r = sr + j * 32;
        *(bf16x8*)&Ws[nxt][r * 72 + se] = Brg[j];
      }
    }
    __syncthreads();
  }

#pragma unroll
  for (int ct = 0; ct < 4; ++ct) {
    float bv = bias[n0 + ct * 16 + c];
#pragma unroll
    for (int mf = 0; mf < 2; ++mf)
#pragma unroll
      for (int r = 0; r < 4; ++r)
        y[(size_t)(m0 + w * 32 + mf * 16 + g * 4 + r) * EE + n0 + ct * 16 + c] =
            acc[mf][ct][r] + bv;
  }
}

// ---------------------------------------------------------------------------
extern "C" void kernel_launch(void* const* d_in, const int* in_sizes, int n_in,
                              void* d_out, int out_size, void* d_ws,
                              size_t ws_size, hipStream_t stream) {
  const float* x = (const float*)d_in[0];
  const float* Wq = (const float*)d_in[1];
  const float* Wk = (const float*)d_in[2];
  const float* Wv = (const float*)d_in[3];
  const float* Wo = (const float*)d_in[4];
  const float* bo = (const float*)d_in[5];
  float* out = (float*)d_out;

  const size_t per = (size_t)NROWS * 64;  // 4,194,304 elems
  ushort* qb = (ushort*)d_ws;                       //  8 MB
  ushort* kb = qb + per;                            //  8 MB
  ushort* vtb = kb + per;                           //  8 MB
  ushort* aob = vtb + per;                          //  8 MB
  ushort* wob = aob + per;                          //  2 MB
  ushort* wqkvb = wob + 1024 * 1024;                // 24 KB (+pad)
  float* pO = (float*)(wqkvb + 16384);              // 2 x 16 MB fp32 partials
  float* lsum = pO + 2 * per;                       // 512 KB

  wqkv_cvt<<<48, 256, 0, stream>>>(Wq, Wk, Wv, wqkvb);
  wcvt<<<512, 256, 0, stream>>>(Wo, wob);
  qkv_mfma<<<dim3(16, 16, 2), 256, 0, stream>>>(x, wqkvb, qb, kb, vtb);
  attn_mfma<<<1024, 256, 0, stream>>>(qb, kb, vtb, pO, lsum);
  attn_combine<<<2048, 256, 0, stream>>>(pO, lsum, aob);
  out_proj_mfma<<<dim3(32, 16), 256, 0, stream>>>(aob, wob, bo, out);
}